// Round 1
// baseline (189.965 us; speedup 1.0000x reference)
//
#include <hip/hip_runtime.h>

// TT embedding lookup: out[t,b,:] = (A @ Bm) @ C for per-lookup gathered core rows.
// P=(216,216,216), Q=(2,4,2), R=(128,128), tables=2, batch=1024.
// core0: [2,216,256]  (A row:  [Q0=2][R0=128])
// core1: [2,216,65536] (Bm row: [R0=128][S=512], S = q1*128 + r1)
// core2: [2,216,256]  (C row:  [R1=128][Q2=2])
// out: [2,1024,16], flat idx (q0*4+q1)*2 + j

#define LOOKUPS 2048          // 2 tables * 1024 batch
#define C1_ROW  65536
#define ROW_F4  128           // 512 floats per Bm row = 128 float4

__global__ __launch_bounds__(256) void tt_lookup_kernel(
    const int* __restrict__ idx32,
    const float* __restrict__ c0,
    const float* __restrict__ c1,
    const float* __restrict__ c2,
    float* __restrict__ out)
{
    __shared__ float lds_a[2][256];

    const int half = threadIdx.x >> 7;       // which lookup within the block
    const int tl   = threadIdx.x & 127;      // thread-in-half
    const int g    = blockIdx.x * 2 + half;  // global lookup id [0,2048)
    const int table = g >> 10;               // g / 1024

    // Runtime int64-vs-int32 detection: indices < 2^31, so an int64 buffer
    // (little-endian) has zero at every odd 32-bit word. P(false hit) ~ 1e-28.
    const bool is64 = (idx32[1] == 0) & (idx32[3] == 0) &
                      (idx32[5] == 0) & (idx32[7] == 0);
    const unsigned int idx = is64
        ? (unsigned int)((const long long*)idx32)[g]
        : (unsigned int)idx32[g];

    // mixed-radix decomposition (compiler emits magic-mul for const division)
    const unsigned int i0  = idx / 46656u;          // / (216*216)
    const unsigned int rem = idx - i0 * 46656u;
    const unsigned int i1  = rem / 216u;
    const unsigned int i2  = rem - i1 * 216u;

    const float* arow = c0 + ((size_t)table * 216 + i0) * 256;
    const float* brow = c1 + ((size_t)table * 216 + i1) * C1_ROW;
    const float* crow = c2 + ((size_t)table * 216 + i2) * 256;

    // Stage A ([2][128]) into LDS — later read as wave-broadcast (free).
    lds_a[half][tl]       = arow[tl];
    lds_a[half][tl + 128] = arow[tl + 128];
    __syncthreads();

    // Stage 1: AB[q0, s] = sum_r A[q0,r] * Bm[r,s]; this thread owns
    // s = 4*tl .. 4*tl+3, coalesced float4 per row (16 B/lane * 128 lanes).
    float4 acc0 = {0.f, 0.f, 0.f, 0.f};
    float4 acc1 = {0.f, 0.f, 0.f, 0.f};
    const float4* b4 = (const float4*)brow + tl;
#pragma unroll 8
    for (int r = 0; r < 128; ++r) {
        const float4 bv = b4[r * ROW_F4];
        const float a0 = lds_a[half][r];
        const float a1 = lds_a[half][128 + r];
        acc0.x += a0 * bv.x; acc0.y += a0 * bv.y;
        acc0.z += a0 * bv.z; acc0.w += a0 * bv.w;
        acc1.x += a1 * bv.x; acc1.y += a1 * bv.y;
        acc1.z += a1 * bv.z; acc1.w += a1 * bv.w;
    }

    // Stage 2: out[q0, q1, j] = sum_r1 AB[q0, q1*128+r1] * C[r1, j].
    // This thread's 4 columns are all within one q1 group:
    const int q1 = tl >> 5;                 // (4*tl)/128
    const int r1 = (tl & 31) * 4;           // base r1 of this thread's columns
    const float4 cA = *(const float4*)(crow + r1 * 2);      // C[r1..r1+1][0..1]
    const float4 cB = *(const float4*)(crow + r1 * 2 + 4);  // C[r1+2..r1+3][0..1]

    float p00 = acc0.x*cA.x + acc0.y*cA.z + acc0.z*cB.x + acc0.w*cB.z; // q0=0,j=0
    float p01 = acc0.x*cA.y + acc0.y*cA.w + acc0.z*cB.y + acc0.w*cB.w; // q0=0,j=1
    float p10 = acc1.x*cA.x + acc1.y*cA.z + acc1.z*cB.x + acc1.w*cB.z; // q0=1,j=0
    float p11 = acc1.x*cA.y + acc1.y*cA.w + acc1.z*cB.y + acc1.w*cB.w; // q0=1,j=1

    // Butterfly-reduce across the 32 lanes sharing this q1 (xor masks < 32
    // stay inside the 32-lane group of the 64-lane wave).
#pragma unroll
    for (int m = 16; m >= 1; m >>= 1) {
        p00 += __shfl_xor(p00, m);
        p01 += __shfl_xor(p01, m);
        p10 += __shfl_xor(p10, m);
        p11 += __shfl_xor(p11, m);
    }

    if ((tl & 31) == 0) {
        float* o = out + (size_t)g * 16;
        o[q1 * 2 + 0]     = p00;   // q0=0
        o[q1 * 2 + 1]     = p01;
        o[8 + q1 * 2 + 0] = p10;   // q0=1
        o[8 + q1 * 2 + 1] = p11;
    }
}

extern "C" void kernel_launch(void* const* d_in, const int* in_sizes, int n_in,
                              void* d_out, int out_size, void* d_ws, size_t ws_size,
                              hipStream_t stream) {
    const int*   idx = (const int*)d_in[0];
    const float* c0  = (const float*)d_in[1];
    const float* c1  = (const float*)d_in[2];
    const float* c2  = (const float*)d_in[3];
    float* out = (float*)d_out;
    tt_lookup_kernel<<<dim3(LOOKUPS / 2), dim3(256), 0, stream>>>(idx, c0, c1, c2, out);
}